// Round 2
// baseline (1031.647 us; speedup 1.0000x reference)
//
#include <hip/hip_runtime.h>
#include <hip/hip_bf16.h>

#define NNX 256
#define CCX 128
#define HHX 4
#define CHDX 32
#define NIJ (NNX*NNX)

typedef __hip_bfloat16 bf16;
typedef __hip_bfloat162 bf162;

__device__ __forceinline__ void load8bf16(const bf16* p, float* f){
  const bf162* p2 = (const bf162*)p;
  #pragma unroll
  for(int t=0;t<4;++t){ float2 xy = __bfloat1622float2(p2[t]); f[2*t]=xy.x; f[2*t+1]=xy.y; }
}

// cmap [C, I, J] -> x [I, J, C]
__global__ __launch_bounds__(256) void k_tin(const float* __restrict__ in, float* __restrict__ out){
  __shared__ float t[32][33];
  const int i = blockIdx.z, jt = blockIdx.x, ct = blockIdx.y;
  const int tx = threadIdx.x, ty = threadIdx.y; // 32, 8
  #pragma unroll
  for(int k=0;k<32;k+=8){
    int c = ct*32 + ty + k;
    t[ty+k][tx] = in[(size_t)c*NIJ + (size_t)i*NNX + jt*32 + tx];
  }
  __syncthreads();
  #pragma unroll
  for(int k=0;k<32;k+=8){
    int j = jt*32 + ty + k;
    out[((size_t)i*NNX + j)*CCX + ct*32 + tx] = t[tx][ty+k];
  }
}

// x [I,J,C] -> out [C,I,J]
__global__ __launch_bounds__(256) void k_tout(const float* __restrict__ x, float* __restrict__ out){
  __shared__ float t[32][33];
  const int i = blockIdx.z, jt = blockIdx.x, ct = blockIdx.y;
  const int tx = threadIdx.x, ty = threadIdx.y;
  #pragma unroll
  for(int k=0;k<32;k+=8){
    t[ty+k][tx] = x[((size_t)i*NNX + jt*32+ty+k)*CCX + ct*32 + tx];  // t[j_loc][c_loc]
  }
  __syncthreads();
  #pragma unroll
  for(int k=0;k<32;k+=8){
    out[(size_t)(ct*32+ty+k)*NIJ + (size_t)i*NNX + jt*32 + tx] = t[tx][ty+k];
  }
}

// LayerNorm over C=128. One wave per row; thread holds 2 channels.
template<int TRANS>
__global__ __launch_bounds__(256) void k_ln(const float* __restrict__ x,
    const float* __restrict__ w, const float* __restrict__ b, bf16* __restrict__ xln){
  const int r = blockIdx.x*4 + threadIdx.y;
  const int ii = r>>8, jj = r&255;
  const float* src = x + (size_t)(TRANS ? (jj*NNX+ii) : r)*CCX;
  const int c = threadIdx.x*2;
  float2 v = *(const float2*)(src+c);
  float s = v.x+v.y, s2 = v.x*v.x+v.y*v.y;
  #pragma unroll
  for(int off=32; off>0; off>>=1){ s += __shfl_xor(s,off); s2 += __shfl_xor(s2,off); }
  float mu = s*0.0078125f;
  float var = s2*0.0078125f - mu*mu;
  float rs = rsqrtf(var+1e-5f);
  bf162 hp;
  hp.x = __float2bfloat16((v.x-mu)*rs*w[c]+b[c]);
  hp.y = __float2bfloat16((v.y-mu)*rs*w[c+1]+b[c+1]);
  *(bf162*)(xln + (size_t)r*CCX + c) = hp;
}

// x_ln[65536,128] @ {wq,wk,wv,wg}[128,128] (+wz[128,4]) -> q,k,v,g (bf16), tb2 [H][NIJ] (f32)
// block: (64,4) threads, 16 rows per block; each thread: 4 rows x 8 cols
__global__ __launch_bounds__(256) void k_proj(const bf16* __restrict__ xln,
    const float* __restrict__ wq, const float* __restrict__ wk,
    const float* __restrict__ wv, const float* __restrict__ wg,
    const float* __restrict__ wz, const float* __restrict__ bg,
    bf16* __restrict__ qb, bf16* __restrict__ kb, bf16* __restrict__ vb, bf16* __restrict__ gb,
    float* __restrict__ tb2){
  __shared__ float xs[16][CCX];
  const int r0 = blockIdx.x*16;
  const int tx = threadIdx.x, ty = threadIdx.y;
  const int tid = tx + ty*64;
  {
    int row = tid>>4, seg = (tid&15)*8;
    float f[8]; load8bf16(xln + (size_t)(r0+row)*CCX + seg, f);
    #pragma unroll
    for(int t=0;t<8;++t) xs[row][seg+t]=f[t];
  }
  __syncthreads();
  float acc[4][8]; float acctb[4];
  #pragma unroll
  for(int rr=0;rr<4;++rr){ acctb[rr]=0.f;
    #pragma unroll
    for(int k2=0;k2<8;++k2) acc[rr][k2]=0.f; }
  const float* Wm[4] = {wq,wk,wv,wg};
  for(int c=0;c<CCX;++c){
    float xv[4];
    #pragma unroll
    for(int rr=0;rr<4;++rr) xv[rr]=xs[ty*4+rr][c];
    #pragma unroll
    for(int k2=0;k2<8;++k2){
      float wv_ = Wm[k2>>1][c*CCX + (k2&1)*64 + tx];
      #pragma unroll
      for(int rr=0;rr<4;++rr) acc[rr][k2] += xv[rr]*wv_;
    }
    if(tx<HHX){
      float wzv = wz[c*HHX+tx];
      #pragma unroll
      for(int rr=0;rr<4;++rr) acctb[rr]+=xv[rr]*wzv;
    }
  }
  bf16* Om[4] = {qb,kb,vb,gb};
  #pragma unroll
  for(int k2=0;k2<8;++k2){
    const int mat=k2>>1; const int col=(k2&1)*64+tx;
    #pragma unroll
    for(int rr=0;rr<4;++rr){
      float vv = acc[rr][k2];
      if(mat==0) vv *= 0.17677669529663687f;   // CH^-0.5
      if(mat==3) vv += bg[col];
      Om[mat][(size_t)(r0+ty*4+rr)*CCX + col] = __float2bfloat16(vv);
    }
  }
  if(tx<HHX){
    #pragma unroll
    for(int rr=0;rr<4;++rr) tb2[(size_t)tx*NIJ + r0+ty*4+rr] = acctb[rr];
  }
}

// attention for one (i, h): thread = query j, online softmax over kk
__global__ __launch_bounds__(256) void k_attn(const bf16* __restrict__ qp, const bf16* __restrict__ kp,
       const bf16* __restrict__ vp, const bf16* __restrict__ gp,
       const float* __restrict__ tb2, bf16* __restrict__ op){
  __shared__ float Ks[NNX][CHDX];
  __shared__ float Vs[NNX][CHDX];
  const int i = blockIdx.x, h = blockIdx.y;
  const int tid = threadIdx.x;
  for(int idx=tid; idx<NNX*CHDX/8; idx+=256){
    int row = idx>>2, seg=(idx&3)*8;
    size_t src = ((size_t)(i*NNX+row))*CCX + h*CHDX + seg;
    float f[8];
    load8bf16(kp + src, f);
    #pragma unroll
    for(int t=0;t<8;++t) Ks[row][seg+t]=f[t];
    load8bf16(vp + src, f);
    #pragma unroll
    for(int t=0;t<8;++t) Vs[row][seg+t]=f[t];
  }
  __syncthreads();
  const int j = tid;
  const size_t rbase = ((size_t)(i*NNX+j))*CCX + h*CHDX;
  float qv[CHDX];
  load8bf16(qp + rbase +  0, qv+0);
  load8bf16(qp + rbase +  8, qv+8);
  load8bf16(qp + rbase + 16, qv+16);
  load8bf16(qp + rbase + 24, qv+24);
  const float* tbq = tb2 + (size_t)h*NIJ + (size_t)j*NNX;
  float m=-1e30f, l=0.f, acc[CHDX];
  #pragma unroll
  for(int d=0;d<CHDX;++d) acc[d]=0.f;
  for(int kk=0;kk<NNX;++kk){
    float s = tbq[kk];
    const float* kr = Ks[kk];
    #pragma unroll
    for(int d=0;d<CHDX;++d) s += qv[d]*kr[d];
    float mn = fmaxf(m,s);
    float corr = __expf(m-mn);
    float pv = __expf(s-mn);
    l = l*corr + pv;
    const float* vr = Vs[kk];
    #pragma unroll
    for(int d=0;d<CHDX;++d) acc[d] = acc[d]*corr + pv*vr[d];
    m = mn;
  }
  float linv = 1.0f/l;
  float gv[CHDX];
  load8bf16(gp + rbase +  0, gv+0);
  load8bf16(gp + rbase +  8, gv+8);
  load8bf16(gp + rbase + 16, gv+16);
  load8bf16(gp + rbase + 24, gv+24);
  bf16* dst = op + rbase;
  #pragma unroll
  for(int d=0;d<CHDX;d+=2){
    float o0 = acc[d]*linv / (1.f + __expf(-gv[d]));
    float o1 = acc[d+1]*linv / (1.f + __expf(-gv[d+1]));
    bf162 hp; hp.x=__float2bfloat16(o0); hp.y=__float2bfloat16(o1);
    *(bf162*)(dst+d)=hp;
  }
}

// o[65536,128] @ wo[128,128] + bo, residual add into x (optionally transposed)
template<int TRANS>
__global__ __launch_bounds__(256) void k_oproj(const bf16* __restrict__ ob,
    const float* __restrict__ wo, const float* __restrict__ bo, float* __restrict__ x){
  __shared__ float os[16][CCX];
  const int r0 = blockIdx.x*16;
  const int tx = threadIdx.x, ty = threadIdx.y;
  const int tid = tx + ty*64;
  {
    int row=tid>>4, seg=(tid&15)*8;
    float f[8]; load8bf16(ob + (size_t)(r0+row)*CCX + seg, f);
    #pragma unroll
    for(int t=0;t<8;++t) os[row][seg+t]=f[t];
  }
  __syncthreads();
  float acc[4][2];
  #pragma unroll
  for(int rr=0;rr<4;++rr){ acc[rr][0]=0.f; acc[rr][1]=0.f; }
  for(int c=0;c<CCX;++c){
    float xv[4];
    #pragma unroll
    for(int rr=0;rr<4;++rr) xv[rr]=os[ty*4+rr][c];
    float w0 = wo[c*CCX+tx], w1 = wo[c*CCX+64+tx];
    #pragma unroll
    for(int rr=0;rr<4;++rr){ acc[rr][0]+=xv[rr]*w0; acc[rr][1]+=xv[rr]*w1; }
  }
  #pragma unroll
  for(int rr=0;rr<4;++rr){
    int r = r0+ty*4+rr; int ii=r>>8, jj=r&255;
    size_t base = (size_t)(TRANS ? (jj*NNX+ii) : r)*CCX;
    x[base+tx]    += acc[rr][0] + bo[tx];
    x[base+64+tx] += acc[rr][1] + bo[64+tx];
  }
}

extern "C" void kernel_launch(void* const* d_in, const int* in_sizes, int n_in,
                              void* d_out, int out_size, void* d_ws, size_t ws_size,
                              hipStream_t stream){
  const float* cmap = (const float*)d_in[0];
  char* ws = (char*)d_ws;
  // layout (bytes):
  //   x    [0,          33554432)   f32 [65536][128]
  //   xln  [33554432,   50331648)   bf16 — dead after k_proj; ob aliases it
  //   qb   [50331648,   67108864)
  //   kb   [67108864,   83886080)
  //   vb   [83886080,  100663296)
  //   gb   [100663296, 117440512)
  //   tb2  [117440512, 118489088)   f32 [4][65536]
  float* x   = (float*)(ws);
  bf16* xln  = (bf16*)(ws + 33554432);
  bf16* ob   = xln;                      // alias: xln dead after k_proj
  bf16* qb   = (bf16*)(ws + 50331648);
  bf16* kb   = (bf16*)(ws + 67108864);
  bf16* vb   = (bf16*)(ws + 83886080);
  bf16* gb   = (bf16*)(ws + 100663296);
  float* tb2 = (float*)(ws + 117440512);
  float* outp = (float*)d_out;

  k_tin<<<dim3(8,4,NNX), dim3(32,8), 0, stream>>>(cmap, x);

  for(int p=0;p<2;++p){
    const int b = 1 + 10*p;
    const float* lnw = (const float*)d_in[b+0];
    const float* lnb = (const float*)d_in[b+1];
    const float* wq  = (const float*)d_in[b+2];
    const float* wk  = (const float*)d_in[b+3];
    const float* wv  = (const float*)d_in[b+4];
    const float* wz  = (const float*)d_in[b+5];
    const float* wg  = (const float*)d_in[b+6];
    const float* bg  = (const float*)d_in[b+7];
    const float* wo  = (const float*)d_in[b+8];
    const float* bo  = (const float*)d_in[b+9];

    if(p==0) k_ln<0><<<NIJ/4, dim3(64,4), 0, stream>>>(x, lnw, lnb, xln);
    else     k_ln<1><<<NIJ/4, dim3(64,4), 0, stream>>>(x, lnw, lnb, xln);

    k_proj<<<NIJ/16, dim3(64,4), 0, stream>>>(xln, wq, wk, wv, wg, wz, bg,
                                              qb, kb, vb, gb, tb2);

    k_attn<<<dim3(NNX,HHX), 256, 0, stream>>>(qb, kb, vb, gb, tb2, ob);

    if(p==0) k_oproj<0><<<NIJ/16, dim3(64,4), 0, stream>>>(ob, wo, bo, x);
    else     k_oproj<1><<<NIJ/16, dim3(64,4), 0, stream>>>(ob, wo, bo, x);
  }

  k_tout<<<dim3(8,4,NNX), dim3(32,8), 0, stream>>>(x, outp);
}

// Round 3
// 447.234 us; speedup vs baseline: 2.3067x; 2.3067x over previous
//
#include <hip/hip_runtime.h>
#include <hip/hip_bf16.h>

#define NNX 256
#define CCX 128
#define HHX 4
#define CHDX 32
#define NIJ (NNX*NNX)

typedef __hip_bfloat16 bf16;
typedef __hip_bfloat162 bf162;
typedef __attribute__((ext_vector_type(8))) short short8v;
typedef __attribute__((ext_vector_type(4))) float float4v;

__device__ __forceinline__ float4v MFMA(short8v a, short8v b, float4v c){
  return __builtin_amdgcn_mfma_f32_16x16x32_bf16(a, b, c, 0, 0, 0);
}

__device__ __forceinline__ unsigned pk2(float a, float b){
  unsigned short ua = __bfloat16_as_ushort(__float2bfloat16(a));
  unsigned short ub = __bfloat16_as_ushort(__float2bfloat16(b));
  return (unsigned)ua | ((unsigned)ub << 16);
}
__device__ __forceinline__ float ubf(unsigned short u){
  return __bfloat162float(__ushort_as_bfloat16(u));
}

__device__ __forceinline__ void load8bf16(const bf16* p, float* f){
  const bf162* p2 = (const bf162*)p;
  #pragma unroll
  for(int t=0;t<4;++t){ float2 xy = __bfloat1622float2(p2[t]); f[2*t]=xy.x; f[2*t+1]=xy.y; }
}

// cmap [C, I, J] -> x [I, J, C]
__global__ __launch_bounds__(256) void k_tin(const float* __restrict__ in, float* __restrict__ out){
  __shared__ float t[32][33];
  const int i = blockIdx.z, jt = blockIdx.x, ct = blockIdx.y;
  const int tx = threadIdx.x, ty = threadIdx.y; // 32, 8
  #pragma unroll
  for(int k=0;k<32;k+=8){
    int c = ct*32 + ty + k;
    t[ty+k][tx] = in[(size_t)c*NIJ + (size_t)i*NNX + jt*32 + tx];
  }
  __syncthreads();
  #pragma unroll
  for(int k=0;k<32;k+=8){
    int j = jt*32 + ty + k;
    out[((size_t)i*NNX + j)*CCX + ct*32 + tx] = t[tx][ty+k];
  }
}

// x [I,J,C] -> out [C,I,J]
__global__ __launch_bounds__(256) void k_tout(const float* __restrict__ x, float* __restrict__ out){
  __shared__ float t[32][33];
  const int i = blockIdx.z, jt = blockIdx.x, ct = blockIdx.y;
  const int tx = threadIdx.x, ty = threadIdx.y;
  #pragma unroll
  for(int k=0;k<32;k+=8){
    t[ty+k][tx] = x[((size_t)i*NNX + jt*32+ty+k)*CCX + ct*32 + tx];
  }
  __syncthreads();
  #pragma unroll
  for(int k=0;k<32;k+=8){
    out[(size_t)(ct*32+ty+k)*NIJ + (size_t)i*NNX + jt*32 + tx] = t[tx][ty+k];
  }
}

// fused LayerNorm + triangle-bias projection. One wave per row, thread = 2 channels.
template<int TRANS>
__global__ __launch_bounds__(256) void k_lntb(const float* __restrict__ x,
    const float* __restrict__ w, const float* __restrict__ b,
    const float* __restrict__ wz, bf16* __restrict__ xln, float* __restrict__ tb2){
  const int r = blockIdx.x*4 + threadIdx.y;
  const int ii = r>>8, jj = r&255;
  const float* src = x + (size_t)(TRANS ? (jj*NNX+ii) : r)*CCX;
  const int c = threadIdx.x*2;
  float2 v = *(const float2*)(src+c);
  float s = v.x+v.y, s2 = v.x*v.x+v.y*v.y;
  #pragma unroll
  for(int off=32; off>0; off>>=1){ s += __shfl_xor(s,off); s2 += __shfl_xor(s2,off); }
  float mu = s*0.0078125f;
  float var = s2*0.0078125f - mu*mu;
  float rs = rsqrtf(var+1e-5f);
  float a0 = (v.x-mu)*rs*w[c]+b[c];
  float a1 = (v.y-mu)*rs*w[c+1]+b[c+1];
  bf162 hp; hp.x = __float2bfloat16(a0); hp.y = __float2bfloat16(a1);
  *(bf162*)(xln + (size_t)r*CCX + c) = hp;
  // tb = x_ln @ wz  (wz: [128][4])
  float acc[4];
  #pragma unroll
  for(int hh=0;hh<4;++hh) acc[hh] = a0*wz[c*4+hh] + a1*wz[(c+1)*4+hh];
  #pragma unroll
  for(int off=32; off>0; off>>=1){
    #pragma unroll
    for(int hh=0;hh<4;++hh) acc[hh] += __shfl_xor(acc[hh], off);
  }
  if(threadIdx.x==0){
    #pragma unroll
    for(int hh=0;hh<4;++hh) tb2[(size_t)hh*NIJ + r] = acc[hh];
  }
}

// convert+transpose weights: wT[n][k] = W_{n/128}[k][n%128], n in [0,512)
__global__ __launch_bounds__(256) void k_cvtw(const float* __restrict__ wq,
    const float* __restrict__ wk, const float* __restrict__ wv,
    const float* __restrict__ wg, bf16* __restrict__ wT){
  int idx = blockIdx.x*256 + threadIdx.x;   // 65536
  int n = idx >> 7, k = idx & 127;
  const float* W = (n<128)?wq:(n<256)?wk:(n<384)?wv:wg;
  int cc = n & 127;
  wT[idx] = __float2bfloat16(W[k*CCX + cc]);
}

// MFMA projection: out^T tiles = mfma(A = wT tile [16n x 32k], B = xln^T [32k x 16m])
// block 256 = 4 waves; wave: 32 rows (2 m-subtiles), all 512 cols.
__global__ __launch_bounds__(256) void k_projm(const bf16* __restrict__ xln,
    const bf16* __restrict__ wT, const float* __restrict__ bg,
    bf16* __restrict__ qb, bf16* __restrict__ kb, bf16* __restrict__ vb, bf16* __restrict__ gb){
  const int tid = threadIdx.x;
  const int w = tid >> 6, l = tid & 63;
  const int lq = l & 15, g = l >> 4;
  const int mbase = blockIdx.x*128 + w*32;
  short8v bx[2][4];
  #pragma unroll
  for(int ms=0; ms<2; ++ms){
    const size_t mrow = mbase + ms*16 + lq;
    #pragma unroll
    for(int kc=0; kc<4; ++kc)
      bx[ms][kc] = *(const short8v*)(xln + mrow*CCX + kc*32 + g*8);
  }
  for(int nj=0; nj<32; ++nj){
    float4v acc0 = (float4v)(0.f), acc1 = (float4v)(0.f);
    #pragma unroll
    for(int kc=0; kc<4; ++kc){
      short8v aw = *(const short8v*)(wT + (size_t)(nj*16 + lq)*CCX + kc*32 + g*8);
      acc0 = MFMA(aw, bx[0][kc], acc0);
      acc1 = MFMA(aw, bx[1][kc], acc1);
    }
    const int mat = nj >> 3;
    const int col = (nj&7)*16 + 4*g;
    bf16* outp = (mat==0)?qb:(mat==1)?kb:(mat==2)?vb:gb;
    #pragma unroll
    for(int ms=0; ms<2; ++ms){
      const size_t mrow = mbase + ms*16 + lq;
      float v0 = (ms==0)?acc0[0]:acc1[0], v1 = (ms==0)?acc0[1]:acc1[1];
      float v2 = (ms==0)?acc0[2]:acc1[2], v3 = (ms==0)?acc0[3]:acc1[3];
      if(mat==0){ v0*=0.17677669529663687f; v1*=0.17677669529663687f;
                  v2*=0.17677669529663687f; v3*=0.17677669529663687f; }
      if(mat==3){ v0+=bg[col]; v1+=bg[col+1]; v2+=bg[col+2]; v3+=bg[col+3]; }
      uint2 pw; pw.x = pk2(v0,v1); pw.y = pk2(v2,v3);
      *(uint2*)(outp + mrow*CCX + col) = pw;
    }
  }
}

// MFMA attention per (i,h). 4 waves; wave handles 64 q (4 subtiles of 16).
// S^T = mfma(K_tile, Q^T) ; softmax with tb bias ; O^T = mfma(V^T, P^T).
__global__ __launch_bounds__(256) void k_attnm(const bf16* __restrict__ qp,
    const bf16* __restrict__ kp, const bf16* __restrict__ vp,
    const bf16* __restrict__ gp, const float* __restrict__ tb2,
    bf16* __restrict__ op){
  __shared__ unsigned short KsA[256*32];     // 16KB  K row-major [k][d]
  __shared__ unsigned short VtA[32*256];     // 16KB  V^T [d][k], XOR-swizzled
  __shared__ unsigned short PsA[4*16*256];   // 32KB  per-wave P [q][k], XOR-swizzled
  const int i = blockIdx.x, h = blockIdx.y;
  const int tid = threadIdx.x;
  const int w = tid >> 6, l = tid & 63;
  const int lq = l & 15, g = l >> 4;

  // ---- stage K (row-major) and V^T (swizzled): thread = one k-row ----
  {
    const int k = tid;
    const bf16* ksrc = kp + ((size_t)(i*NNX + k))*CCX + h*CHDX;
    short8v kv0 = *(const short8v*)(ksrc);
    short8v kv1 = *(const short8v*)(ksrc+8);
    short8v kv2 = *(const short8v*)(ksrc+16);
    short8v kv3 = *(const short8v*)(ksrc+24);
    *(short8v*)(&KsA[k*32])      = kv0;
    *(short8v*)(&KsA[k*32+8])    = kv1;
    *(short8v*)(&KsA[k*32+16])   = kv2;
    *(short8v*)(&KsA[k*32+24])   = kv3;
    const bf16* vsrc = vp + ((size_t)(i*NNX + k))*CCX + h*CHDX;
    short8v vv[4];
    vv[0] = *(const short8v*)(vsrc);
    vv[1] = *(const short8v*)(vsrc+8);
    vv[2] = *(const short8v*)(vsrc+16);
    vv[3] = *(const short8v*)(vsrc+24);
    char* vtb = (char*)VtA;
    #pragma unroll
    for(int c4=0;c4<4;++c4){
      #pragma unroll
      for(int e=0;e<8;++e){
        int d = c4*8+e;
        int off = d*512 + ((2*k) ^ ((d&7)<<4));
        *(short*)(vtb + off) = vv[c4][e];
      }
    }
  }
  __syncthreads();

  const char* ktb = (const char*)KsA;
  const char* vtb = (const char*)VtA;
  char* psb = (char*)(PsA + w*16*256);

  #pragma unroll 1
  for(int sub=0; sub<4; ++sub){
    const int q = w*64 + sub*16 + lq;
    const size_t qrow = (size_t)i*NNX + q;
    short8v qf = *(const short8v*)(qp + qrow*CCX + h*CHDX + g*8);
    float4v s[16];
    #pragma unroll
    for(int t=0;t<16;++t){
      short8v ak = *(const short8v*)(ktb + (t*16 + lq)*64 + g*16);
      s[t] = MFMA(ak, qf, (float4v)(0.f));
    }
    // bias + row max (k spread over regs/tiles locally + lane groups 16,32)
    const float* tbq = tb2 + (size_t)h*NIJ + (size_t)q*NNX;
    float m = -1e30f;
    #pragma unroll
    for(int t=0;t<16;++t){
      float4v bb = *(const float4v*)(tbq + t*16 + g*4);
      s[t] += bb;
      m = fmaxf(m, fmaxf(fmaxf(s[t][0], s[t][1]), fmaxf(s[t][2], s[t][3])));
    }
    m = fmaxf(m, __shfl_xor(m,16));
    m = fmaxf(m, __shfl_xor(m,32));
    float lsum = 0.f;
    #pragma unroll
    for(int t=0;t<16;++t){
      #pragma unroll
      for(int r=0;r<4;++r){ float e = __expf(s[t][r]-m); s[t][r]=e; lsum+=e; }
    }
    lsum += __shfl_xor(lsum,16);
    lsum += __shfl_xor(lsum,32);
    const float linv = 1.0f/lsum;
    // write P (bf16, swizzled)
    #pragma unroll
    for(int t=0;t<16;++t){
      uint2 pw; pw.x = pk2(s[t][0], s[t][1]); pw.y = pk2(s[t][2], s[t][3]);
      int off = lq*512 + ((32*t + 8*g) ^ ((lq&7)<<4));
      *(uint2*)(psb + off) = pw;
    }
    // PV: O^T = mfma(A=V^T tile, B=P^T chunk); epilogue gate+store
    #pragma unroll
    for(int dt=0; dt<2; ++dt){
      float4v acc = (float4v)(0.f);
      #pragma unroll
      for(int c=0;c<8;++c){
        const int vrow = dt*16 + lq;
        short8v av = *(const short8v*)(vtb + vrow*512 + ((16*g + 64*c) ^ ((vrow&7)<<4)));
        short8v bp = *(const short8v*)(psb + lq*512 + ((16*g + 64*c) ^ ((lq&7)<<4)));
        acc = MFMA(av, bp, acc);
      }
      const size_t eoff = qrow*CCX + h*CHDX + dt*16 + g*4;
      uint2 gw = *(const uint2*)(gp + eoff);
      float g0 = ubf((unsigned short)(gw.x & 0xffff));
      float g1 = ubf((unsigned short)(gw.x >> 16));
      float g2 = ubf((unsigned short)(gw.y & 0xffff));
      float g3 = ubf((unsigned short)(gw.y >> 16));
      float o0 = acc[0]*linv / (1.f + __expf(-g0));
      float o1 = acc[1]*linv / (1.f + __expf(-g1));
      float o2 = acc[2]*linv / (1.f + __expf(-g2));
      float o3 = acc[3]*linv / (1.f + __expf(-g3));
      uint2 ow; ow.x = pk2(o0,o1); ow.y = pk2(o2,o3);
      *(uint2*)(op + eoff) = ow;
    }
  }
}

// o[65536,128] @ wo[128,128] + bo, residual add into x (optionally transposed)
template<int TRANS>
__global__ __launch_bounds__(256) void k_oproj(const bf16* __restrict__ ob,
    const float* __restrict__ wo, const float* __restrict__ bo, float* __restrict__ x){
  __shared__ float os[16][CCX];
  const int r0 = blockIdx.x*16;
  const int tx = threadIdx.x, ty = threadIdx.y;
  const int tid = tx + ty*64;
  {
    int row=tid>>4, seg=(tid&15)*8;
    float f[8]; load8bf16(ob + (size_t)(r0+row)*CCX + seg, f);
    #pragma unroll
    for(int t=0;t<8;++t) os[row][seg+t]=f[t];
  }
  __syncthreads();
  float acc[4][2];
  #pragma unroll
  for(int rr=0;rr<4;++rr){ acc[rr][0]=0.f; acc[rr][1]=0.f; }
  for(int c=0;c<CCX;++c){
    float xv[4];
    #pragma unroll
    for(int rr=0;rr<4;++rr) xv[rr]=os[ty*4+rr][c];
    float w0 = wo[c*CCX+tx], w1 = wo[c*CCX+64+tx];
    #pragma unroll
    for(int rr=0;rr<4;++rr){ acc[rr][0]+=xv[rr]*w0; acc[rr][1]+=xv[rr]*w1; }
  }
  #pragma unroll
  for(int rr=0;rr<4;++rr){
    int r = r0+ty*4+rr; int ii=r>>8, jj=r&255;
    size_t base = (size_t)(TRANS ? (jj*NNX+ii) : r)*CCX;
    x[base+tx]    += acc[rr][0] + bo[tx];
    x[base+64+tx] += acc[rr][1] + bo[64+tx];
  }
}

extern "C" void kernel_launch(void* const* d_in, const int* in_sizes, int n_in,
                              void* d_out, int out_size, void* d_ws, size_t ws_size,
                              hipStream_t stream){
  const float* cmap = (const float*)d_in[0];
  char* ws = (char*)d_ws;
  // ws layout (bytes):
  //   x    [0,          33554432)   f32 [65536][128]
  //   xln  [33554432,   50331648)   bf16 — dead after k_projm; ob aliases it
  //   qb   [50331648,   67108864)
  //   kb   [67108864,   83886080)
  //   vb   [83886080,  100663296)
  //   gb   [100663296, 117440512)
  //   tb2  [117440512, 118489088)   f32 [4][65536]
  // wT (bf16 [512][128], 128KB) lives at the head of d_out; k_tout overwrites it last.
  float* x   = (float*)(ws);
  bf16* xln  = (bf16*)(ws + 33554432);
  bf16* ob   = xln;
  bf16* qb   = (bf16*)(ws + 50331648);
  bf16* kb   = (bf16*)(ws + 67108864);
  bf16* vb   = (bf16*)(ws + 83886080);
  bf16* gb   = (bf16*)(ws + 100663296);
  float* tb2 = (float*)(ws + 117440512);
  bf16* wT   = (bf16*)d_out;
  float* outp = (float*)d_out;

  k_tin<<<dim3(8,4,NNX), dim3(32,8), 0, stream>>>(cmap, x);

  for(int p=0;p<2;++p){
    const int b = 1 + 10*p;
    const float* lnw = (const float*)d_in[b+0];
    const float* lnb = (const float*)d_in[b+1];
    const float* wq  = (const float*)d_in[b+2];
    const float* wk  = (const float*)d_in[b+3];
    const float* wv  = (const float*)d_in[b+4];
    const float* wz  = (const float*)d_in[b+5];
    const float* wg  = (const float*)d_in[b+6];
    const float* bg  = (const float*)d_in[b+7];
    const float* wo  = (const float*)d_in[b+8];
    const float* bo  = (const float*)d_in[b+9];

    k_cvtw<<<256, 256, 0, stream>>>(wq, wk, wv, wg, wT);

    if(p==0) k_lntb<0><<<NIJ/4, dim3(64,4), 0, stream>>>(x, lnw, lnb, wz, xln, tb2);
    else     k_lntb<1><<<NIJ/4, dim3(64,4), 0, stream>>>(x, lnw, lnb, wz, xln, tb2);

    k_projm<<<NIJ/128, 256, 0, stream>>>(xln, wT, bg, qb, kb, vb, gb);

    k_attnm<<<dim3(NNX,HHX), 256, 0, stream>>>(qb, kb, vb, gb, tb2, ob);

    if(p==0) k_oproj<0><<<NIJ/16, dim3(64,4), 0, stream>>>(ob, wo, bo, x);
    else     k_oproj<1><<<NIJ/16, dim3(64,4), 0, stream>>>(ob, wo, bo, x);
  }

  k_tout<<<dim3(8,4,NNX), dim3(32,8), 0, stream>>>(x, outp);
}